// Round 4
// baseline (65.696 us; speedup 1.0000x reference)
//
#include <hip/hip_runtime.h>

#define NB 32
#define RR 128
#define FF 128
#define FT 64   // f-half width
#define SB 132  // LDS row stride for transposed b: 132*4B = 528B, 16B-aligned rows,
                // 4-way write conflict (~1.58x) on staging, conflict-free b128 reads

// v5: v4 + two-stage f-pipeline (FT=64, double-buffered sh_b).
// v4 post-mortem: XCD swizzle + clustered loads gave -3.2 us (matched
// prediction) -> residual is staging-latency. Ledger: 65.4 = fill 40.2 +
// harness gap ~15 + kernel ~10. Largest addressable term: v4's staging is
// FULLY exposed (issue 18 loads -> drain all -> sync -> compute).
// Fix (T14 issue-early/write-late): stage f-half 0, sync; ISSUE half-1's 8
// float4 loads, compute half-0 (~0.85 us VALU hides the cold-load latency),
// then write half-1 to the other buffer, sync, compute half-1.
// Explicit 2-phase code, <=10 float4 live, all statically named (v2 spill
// lesson). LDS: 2 x 33.8 KB dbuf + 8 KB sh_a = 75.7 KB, 1 block/CU.
// Still no d_ws use: the 268 MB harness poison fill stays the only big HBM user.
__global__ __launch_bounds__(256) void gauss_fused(const float* __restrict__ x1,
                                                   const float* __restrict__ x2,
                                                   const float* __restrict__ sigma,
                                                   const float* __restrict__ mean,
                                                   float* __restrict__ out) {
  __shared__ __align__(16) float sh_b[2][FT * SB];  // 2 x 33792 B, transposed [f][j]
  __shared__ __align__(16) float sh_a[16 * FF];     // 8192 B, 16 x1 rows, mean folded

  // XCD-chunked mapping: dispatch d -> XCD d&7 (round-robin, 8 XCDs).
  // XCD x serves n = 4x .. 4x+3, 8 i-tiles each (grid 256 = 8 XCDs x 4 n x 8 tiles).
  const int d = blockIdx.x;
  const int xcd = d & 7;
  const int k = d >> 3;                  // 0..31 within-XCD slot
  const int n = (xcd << 2) + (k >> 3);   // 4 consecutive n per XCD
  const int i0 = (k & 7) << 4;           // 16 rows per block
  const int tid = threadIdx.x;
  const int tx = tid & 31;   // j-quad
  const int ty = tid >> 5;   // 0..7 -> rows i0+ty and i0+ty+8

  const float mval = mean[0];
  const float sg = sigma[0];
  const float cneg = -1.0f / (2.0f * sg * sg);

  const float* __restrict__ x2base = x2 + (size_t)n * RR * FF;
  const int jj = tid >> 3;        // 0..31: j within each 32-row chunk
  const int fo = (tid & 7) << 2;  // 0,4,...,28: f-quad within each 32-f chunk

  // Per-thread staging footprint per f-half: 2 f-chunks (fc) x 4 j-chunks (p)
  // = 8 float4. Each 8-lane group reads a contiguous 128 B row segment.
#define LDQ(t, fc, p) \
  *(const float4*)(x2base + (size_t)(jj + ((p) << 5)) * FF + (t) * FT + ((fc) << 5) + fo)
#define STW(q, t, fc, p)                              \
  {                                                   \
    const int f0 = ((fc) << 5) + fo;                  \
    const int j = jj + ((p) << 5);                    \
    float* dstp = sh_b[t];                            \
    dstp[(f0 + 0) * SB + j] = (q).x;                  \
    dstp[(f0 + 1) * SB + j] = (q).y;                  \
    dstp[(f0 + 2) * SB + j] = (q).z;                  \
    dstp[(f0 + 3) * SB + j] = (q).w;                  \
  }

  float acc00 = 0.f, acc01 = 0.f, acc02 = 0.f, acc03 = 0.f;
  float acc10 = 0.f, acc11 = 0.f, acc12 = 0.f, acc13 = 0.f;
  const int j0 = tx << 2;
  const float* __restrict__ arow0 = sh_a + ty * FF;
  const float* __restrict__ arow1 = sh_a + (ty + 8) * FF;

  // Compute one f-half from sh_b[t]: 16 fq x 4 c, 8 FMAs per b128 read.
#define COMPUTE_HALF(t)                                                          \
  {                                                                              \
    const float* __restrict__ bb = sh_b[t];                                      \
    _Pragma("unroll 4") for (int fq = 0; fq < 16; ++fq) {                        \
      const float4 a0 = *(const float4*)(arow0 + (t) * FT + (fq << 2));          \
      const float4 a1 = *(const float4*)(arow1 + (t) * FT + (fq << 2));          \
      _Pragma("unroll") for (int c = 0; c < 4; ++c) {                            \
        const float4 b = *(const float4*)(bb + ((fq << 2) + c) * SB + j0);       \
        const float a0c = (c == 0) ? a0.x : (c == 1) ? a0.y : (c == 2) ? a0.z : a0.w; \
        const float a1c = (c == 0) ? a1.x : (c == 1) ? a1.y : (c == 2) ? a1.z : a1.w; \
        float dd;                                                                \
        dd = a0c - b.x; acc00 = fmaf(dd, dd, acc00);                             \
        dd = a0c - b.y; acc01 = fmaf(dd, dd, acc01);                             \
        dd = a0c - b.z; acc02 = fmaf(dd, dd, acc02);                             \
        dd = a0c - b.w; acc03 = fmaf(dd, dd, acc03);                             \
        dd = a1c - b.x; acc10 = fmaf(dd, dd, acc10);                             \
        dd = a1c - b.y; acc11 = fmaf(dd, dd, acc11);                             \
        dd = a1c - b.z; acc12 = fmaf(dd, dd, acc12);                             \
        dd = a1c - b.w; acc13 = fmaf(dd, dd, acc13);                             \
      }                                                                          \
    }                                                                            \
  }

  // ---- stage 0: half-0 b-loads + a-loads clustered, drain, sync ----
  {
    float4 q0 = LDQ(0, 0, 0), q1 = LDQ(0, 0, 1), q2 = LDQ(0, 0, 2), q3 = LDQ(0, 0, 3);
    float4 q4 = LDQ(0, 1, 0), q5 = LDQ(0, 1, 1), q6 = LDQ(0, 1, 2), q7 = LDQ(0, 1, 3);
    const float4* asrc = (const float4*)(x1 + (size_t)(n * RR + i0) * FF);
    const float4 v0 = asrc[tid];
    const float4 v1 = asrc[tid + 256];
    ((float4*)sh_a)[tid] = make_float4(v0.x - mval, v0.y - mval, v0.z - mval, v0.w - mval);
    ((float4*)sh_a)[tid + 256] = make_float4(v1.x - mval, v1.y - mval, v1.z - mval, v1.w - mval);
    STW(q0, 0, 0, 0) STW(q1, 0, 0, 1) STW(q2, 0, 0, 2) STW(q3, 0, 0, 3)
    STW(q4, 0, 1, 0) STW(q5, 0, 1, 1) STW(q6, 0, 1, 2) STW(q7, 0, 1, 3)
  }
  __syncthreads();

  // ---- issue half-1 loads EARLY; compute half-0 while they fly ----
  {
    float4 q0 = LDQ(1, 0, 0), q1 = LDQ(1, 0, 1), q2 = LDQ(1, 0, 2), q3 = LDQ(1, 0, 3);
    float4 q4 = LDQ(1, 1, 0), q5 = LDQ(1, 1, 1), q6 = LDQ(1, 1, 2), q7 = LDQ(1, 1, 3);

    COMPUTE_HALF(0)

    // write-late: drain half-1 into the other buffer (no reader until sync)
    STW(q0, 1, 0, 0) STW(q1, 1, 0, 1) STW(q2, 1, 0, 2) STW(q3, 1, 0, 3)
    STW(q4, 1, 1, 0) STW(q5, 1, 1, 1) STW(q6, 1, 1, 2) STW(q7, 1, 1, 3)
  }
  __syncthreads();

  COMPUTE_HALF(1)
#undef LDQ
#undef STW
#undef COMPUTE_HALF

  // kernel_value = exp(-ds / (2 sigma^2)); softmax over j for BOTH rows.
  // Row = 32 lanes x 4 regs; xor offsets <32 stay within each 32-lane half.
  const float k00 = __expf(acc00 * cneg);
  const float k01 = __expf(acc01 * cneg);
  const float k02 = __expf(acc02 * cneg);
  const float k03 = __expf(acc03 * cneg);
  const float k10 = __expf(acc10 * cneg);
  const float k11 = __expf(acc11 * cneg);
  const float k12 = __expf(acc12 * cneg);
  const float k13 = __expf(acc13 * cneg);

  float mx0 = fmaxf(fmaxf(k00, k01), fmaxf(k02, k03));
  float mx1 = fmaxf(fmaxf(k10, k11), fmaxf(k12, k13));
#pragma unroll
  for (int off = 16; off >= 1; off >>= 1) {
    mx0 = fmaxf(mx0, __shfl_xor(mx0, off, 64));
    mx1 = fmaxf(mx1, __shfl_xor(mx1, off, 64));
  }
  const float e00 = __expf(k00 - mx0);
  const float e01 = __expf(k01 - mx0);
  const float e02 = __expf(k02 - mx0);
  const float e03 = __expf(k03 - mx0);
  const float e10 = __expf(k10 - mx1);
  const float e11 = __expf(k11 - mx1);
  const float e12 = __expf(k12 - mx1);
  const float e13 = __expf(k13 - mx1);
  float s0 = e00 + e01 + e02 + e03;
  float s1 = e10 + e11 + e12 + e13;
#pragma unroll
  for (int off = 16; off >= 1; off >>= 1) {
    s0 += __shfl_xor(s0, off, 64);
    s1 += __shfl_xor(s1, off, 64);
  }
  const float r0 = 1.0f / s0;
  const float r1 = 1.0f / s1;

  *(float4*)(out + (size_t)(n * RR + i0 + ty) * RR + j0) =
      make_float4(e00 * r0, e01 * r0, e02 * r0, e03 * r0);
  *(float4*)(out + (size_t)(n * RR + i0 + ty + 8) * RR + j0) =
      make_float4(e10 * r1, e11 * r1, e12 * r1, e13 * r1);
}

extern "C" void kernel_launch(void* const* d_in, const int* in_sizes, int n_in,
                              void* d_out, int out_size, void* d_ws, size_t ws_size,
                              hipStream_t stream) {
  const float* x1 = (const float*)d_in[0];
  const float* x2 = (const float*)d_in[1];
  const float* sigma = (const float*)d_in[2];
  const float* mean = (const float*)d_in[3];
  float* out = (float*)d_out;
  (void)d_ws; (void)ws_size;  // deliberately unused: keep the 268 MB ws poison off our path

  gauss_fused<<<dim3(NB * 8), dim3(256), 0, stream>>>(x1, x2, sigma, mean, out);
}